// Round 1
// baseline (2307.836 us; speedup 1.0000x reference)
//
#include <hip/hip_runtime.h>
#include <hip/hip_bf16.h>
#include <cstdint>

#define N_TOK 16384
#define DMODEL 2048
#define FFH    3072
#define NEXP   8
#define ATOT   32768   // N_TOK * TOP_K

typedef __bf16 bf16;
typedef __attribute__((ext_vector_type(8))) __bf16 bf16x8;
typedef __attribute__((ext_vector_type(4))) __bf16 bf16x4;
typedef __attribute__((ext_vector_type(4))) float  f32x4;

__device__ __forceinline__ void gl_lds16(const bf16* g, void* l) {
  __builtin_amdgcn_global_load_lds(
      (const __attribute__((address_space(1))) void*)g,
      (__attribute__((address_space(3))) void*)l, 16, 0, 0);
}

// ---------------- fp32 -> bf16 conversion (vectorized) ----------------
__global__ void cvt_f32_bf16(const float* __restrict__ src, bf16* __restrict__ dst, long n4) {
  long i = (long)blockIdx.x * blockDim.x + threadIdx.x;
  if (i >= n4) return;
  const float4 v = ((const float4*)src)[i];
  bf16x4 o;
  o.x = (bf16)v.x; o.y = (bf16)v.y; o.z = (bf16)v.z; o.w = (bf16)v.w;
  ((bf16x4*)dst)[i] = o;
}

// ---------------- router: logits, top-2, renormalized weights ----------------
__global__ void router_k(const float* __restrict__ x, const float* __restrict__ rw,
                         int* __restrict__ tk_e, float* __restrict__ tk_w,
                         int* __restrict__ cnt) {
  const int wv = threadIdx.x >> 6, lane = threadIdx.x & 63;
  const int t = blockIdx.x * 4 + wv;
  const float* xr = x + (size_t)t * DMODEL;
  float acc[NEXP];
#pragma unroll
  for (int e = 0; e < NEXP; ++e) acc[e] = 0.f;
  for (int k = lane; k < DMODEL; k += 64) {
    const float xv = xr[k];
#pragma unroll
    for (int e = 0; e < NEXP; ++e) acc[e] = fmaf(xv, rw[e * DMODEL + k], acc[e]);
  }
#pragma unroll
  for (int e = 0; e < NEXP; ++e) {
#pragma unroll
    for (int o = 32; o; o >>= 1) acc[e] += __shfl_xor(acc[e], o, 64);
  }
  if (lane == 0) {
    int e0 = 0; float v0 = acc[0];
#pragma unroll
    for (int e = 1; e < NEXP; ++e) if (acc[e] > v0) { v0 = acc[e]; e0 = e; }
    int e1 = -1; float v1 = -1e30f;
#pragma unroll
    for (int e = 0; e < NEXP; ++e) if (e != e0 && acc[e] > v1) { v1 = acc[e]; e1 = e; }
    // top-2 softmax renormalized: w0 = p0/(p0+p1) = 1/(1+exp(l1-l0))
    const float w0 = 1.f / (1.f + __expf(v1 - v0));
    tk_e[t * 2] = e0; tk_e[t * 2 + 1] = e1;
    tk_w[t * 2] = w0; tk_w[t * 2 + 1] = 1.f - w0;
    atomicAdd(&cnt[e0], 1); atomicAdd(&cnt[e1], 1);
  }
}

// ---------------- per-expert offsets (exclusive prefix over 8) ----------------
__global__ void offs_k(const int* __restrict__ cnt, int* __restrict__ offs) {
  if (threadIdx.x == 0) {
    int o = 0;
    for (int e = 0; e < NEXP; ++e) { offs[e] = o; o += cnt[e]; }
  }
}

// ---------------- scatter token ids into per-expert lists ----------------
__global__ void scatter_k(const int* __restrict__ tk_e, const float* __restrict__ tk_w,
                          const int* __restrict__ offs, int* __restrict__ cnt2,
                          int* __restrict__ tok_list, float* __restrict__ w_list) {
  const int t = blockIdx.x * 256 + threadIdx.x;
  if (t >= N_TOK) return;
#pragma unroll
  for (int k = 0; k < 2; ++k) {
    const int e = tk_e[t * 2 + k];
    const int p = atomicAdd(&cnt2[e], 1);
    tok_list[offs[e] + p] = t;
    w_list[offs[e] + p] = tk_w[t * 2 + k];
  }
}

// ---------------- GEMM1: h = silu(Xe@Gw^T) * (Xe@Uw^T), gathered rows ----------------
__global__ __launch_bounds__(256, 2) void gemm_gu_k(
    const bf16* __restrict__ xb, const bf16* __restrict__ gw, const bf16* __restrict__ uw,
    bf16* __restrict__ hbuf, const int* __restrict__ tok_list,
    const int* __restrict__ cnt, const int* __restrict__ offs) {
  const int e = blockIdx.z;
  const int cn = cnt[e];
  const int mbase = blockIdx.y * 128;
  if (mbase >= cn) return;
  const int offE = offs[e];
  const int nbase = blockIdx.x * 128;

  __shared__ bf16 lA[128 * 32], lG[128 * 32], lU[128 * 32];

  const int tid = threadIdx.x;
  const int wv = tid >> 6, lane = tid & 63;
  const int wr = wv >> 1, wc = wv & 1;

  // staging geometry: chunk c covers rows c*64 + tid/4, 16B at byte col (tid&3)*16
  const int r0 = tid >> 2, r1 = r0 + 64;
  const int colel = (tid & 3) * 8;

  const int tok0 = tok_list[offE + min(mbase + r0, cn - 1)];
  const int tok1 = tok_list[offE + min(mbase + r1, cn - 1)];
  const bf16* gA0 = xb + (size_t)tok0 * DMODEL + colel;
  const bf16* gA1 = xb + (size_t)tok1 * DMODEL + colel;
  const bf16* gG0 = gw + ((size_t)e * FFH + nbase + r0) * DMODEL + colel;
  const bf16* gG1 = gw + ((size_t)e * FFH + nbase + r1) * DMODEL + colel;
  const bf16* gU0 = uw + ((size_t)e * FFH + nbase + r0) * DMODEL + colel;
  const bf16* gU1 = uw + ((size_t)e * FFH + nbase + r1) * DMODEL + colel;

  char* lAw = (char*)lA + wv * 1024;
  char* lGw = (char*)lG + wv * 1024;
  char* lUw = (char*)lU + wv * 1024;

  const f32x4 zero = {0.f, 0.f, 0.f, 0.f};
  f32x4 accG[4][4], accU[4][4];
#pragma unroll
  for (int i = 0; i < 4; ++i)
#pragma unroll
    for (int j = 0; j < 4; ++j) { accG[i][j] = zero; accU[i][j] = zero; }

  const int aoff = (wr * 64 + (lane & 15)) * 64 + (lane >> 4) * 16;
  const int boff = (wc * 64 + (lane & 15)) * 64 + (lane >> 4) * 16;

  for (int kk = 0; kk < DMODEL / 32; ++kk) {
    const int k0 = kk * 32;
    __syncthreads();
    gl_lds16(gA0 + k0, lAw);
    gl_lds16(gA1 + k0, lAw + 4096);
    gl_lds16(gG0 + k0, lGw);
    gl_lds16(gG1 + k0, lGw + 4096);
    gl_lds16(gU0 + k0, lUw);
    gl_lds16(gU1 + k0, lUw + 4096);
    __syncthreads();
    bf16x8 a[4], bg[4], bu[4];
#pragma unroll
    for (int i = 0; i < 4; ++i) {
      a[i]  = *(const bf16x8*)((const char*)lA + aoff + i * 16 * 64);
      bg[i] = *(const bf16x8*)((const char*)lG + boff + i * 16 * 64);
      bu[i] = *(const bf16x8*)((const char*)lU + boff + i * 16 * 64);
    }
#pragma unroll
    for (int mi = 0; mi < 4; ++mi)
#pragma unroll
      for (int ni = 0; ni < 4; ++ni) {
        accG[mi][ni] = __builtin_amdgcn_mfma_f32_16x16x32_bf16(a[mi], bg[ni], accG[mi][ni], 0, 0, 0);
        accU[mi][ni] = __builtin_amdgcn_mfma_f32_16x16x32_bf16(a[mi], bu[ni], accU[mi][ni], 0, 0, 0);
      }
  }

  // epilogue: silu(g)*u -> bf16 h rows (C/D layout: col=lane&15, row=(lane>>4)*4+j)
#pragma unroll
  for (int mi = 0; mi < 4; ++mi)
#pragma unroll
    for (int j = 0; j < 4; ++j) {
      const int mloc = wr * 64 + mi * 16 + (lane >> 4) * 4 + j;
      if (mbase + mloc < cn) {
        bf16* hr = hbuf + (size_t)(offE + mbase + mloc) * FFH + nbase + wc * 64 + (lane & 15);
#pragma unroll
        for (int ni = 0; ni < 4; ++ni) {
          const float g = accG[mi][ni][j], u = accU[mi][ni][j];
          hr[ni * 16] = (bf16)(g / (1.f + __expf(-g)) * u);
        }
      }
    }
}

// ---------------- GEMM2: out[tok] += w * (h @ Dw^T), scatter-add ----------------
__global__ __launch_bounds__(256, 2) void gemm_down_k(
    const bf16* __restrict__ hbuf, const bf16* __restrict__ dw, float* __restrict__ out,
    const int* __restrict__ tok_list, const float* __restrict__ w_list,
    const int* __restrict__ cnt, const int* __restrict__ offs) {
  const int e = blockIdx.z;
  const int cn = cnt[e];
  const int mbase = blockIdx.y * 128;
  if (mbase >= cn) return;
  const int offE = offs[e];
  const int nbase = blockIdx.x * 128;

  __shared__ bf16 lA[128 * 32], lB[128 * 32];

  const int tid = threadIdx.x;
  const int wv = tid >> 6, lane = tid & 63;
  const int wr = wv >> 1, wc = wv & 1;

  const int r0 = tid >> 2, r1 = r0 + 64;
  const int colel = (tid & 3) * 8;

  // A rows are contiguous assignment indices (hbuf is per-assignment); rows past cn
  // read harmless in-bounds garbage (hbuf padded by 128 rows) and are not stored.
  const bf16* gA0 = hbuf + (size_t)(offE + mbase + r0) * FFH + colel;
  const bf16* gA1 = hbuf + (size_t)(offE + mbase + r1) * FFH + colel;
  const bf16* gB0 = dw + ((size_t)e * DMODEL + nbase + r0) * FFH + colel;
  const bf16* gB1 = dw + ((size_t)e * DMODEL + nbase + r1) * FFH + colel;

  char* lAw = (char*)lA + wv * 1024;
  char* lBw = (char*)lB + wv * 1024;

  const f32x4 zero = {0.f, 0.f, 0.f, 0.f};
  f32x4 acc[4][4];
#pragma unroll
  for (int i = 0; i < 4; ++i)
#pragma unroll
    for (int j = 0; j < 4; ++j) acc[i][j] = zero;

  const int aoff = (wr * 64 + (lane & 15)) * 64 + (lane >> 4) * 16;
  const int boff = (wc * 64 + (lane & 15)) * 64 + (lane >> 4) * 16;

  for (int kk = 0; kk < FFH / 32; ++kk) {
    const int k0 = kk * 32;
    __syncthreads();
    gl_lds16(gA0 + k0, lAw);
    gl_lds16(gA1 + k0, lAw + 4096);
    gl_lds16(gB0 + k0, lBw);
    gl_lds16(gB1 + k0, lBw + 4096);
    __syncthreads();
    bf16x8 a[4], b[4];
#pragma unroll
    for (int i = 0; i < 4; ++i) {
      a[i] = *(const bf16x8*)((const char*)lA + aoff + i * 16 * 64);
      b[i] = *(const bf16x8*)((const char*)lB + boff + i * 16 * 64);
    }
#pragma unroll
    for (int mi = 0; mi < 4; ++mi)
#pragma unroll
      for (int ni = 0; ni < 4; ++ni)
        acc[mi][ni] = __builtin_amdgcn_mfma_f32_16x16x32_bf16(a[mi], b[ni], acc[mi][ni], 0, 0, 0);
  }

#pragma unroll
  for (int mi = 0; mi < 4; ++mi)
#pragma unroll
    for (int j = 0; j < 4; ++j) {
      const int mloc = wr * 64 + mi * 16 + (lane >> 4) * 4 + j;
      if (mbase + mloc < cn) {
        const int ar = offE + mbase + mloc;
        const int tok = tok_list[ar];
        const float wg = w_list[ar];
        float* orow = out + (size_t)tok * DMODEL + nbase + wc * 64 + (lane & 15);
#pragma unroll
        for (int ni = 0; ni < 4; ++ni)
          atomicAdd(&orow[ni * 16], wg * acc[mi][ni][j]);
      }
    }
}

extern "C" void kernel_launch(void* const* d_in, const int* in_sizes, int n_in,
                              void* d_out, int out_size, void* d_ws, size_t ws_size,
                              hipStream_t stream) {
  const float* x  = (const float*)d_in[0];
  const float* rw = (const float*)d_in[1];
  const float* gw = (const float*)d_in[2];
  const float* uw = (const float*)d_in[3];
  const float* dw = (const float*)d_in[4];
  float* out = (float*)d_out;

  char* ws = (char*)d_ws;
  size_t o = 0;
  auto alloc = [&](size_t bytes) {
    void* p = ws + o;
    o = (o + bytes + 255) & ~(size_t)255;
    return p;
  };

  bf16*  xb       = (bf16*)alloc((size_t)N_TOK * DMODEL * 2);
  bf16*  gwb      = (bf16*)alloc((size_t)NEXP * FFH * DMODEL * 2);
  bf16*  uwb      = (bf16*)alloc((size_t)NEXP * FFH * DMODEL * 2);
  bf16*  dwb      = (bf16*)alloc((size_t)NEXP * DMODEL * FFH * 2);
  bf16*  hbuf     = (bf16*)alloc((size_t)(ATOT + 128) * FFH * 2);
  int*   tok_list = (int*)alloc((ATOT + 128) * 4);
  float* w_list   = (float*)alloc((ATOT + 128) * 4);
  int*   tk_e     = (int*)alloc((size_t)N_TOK * 2 * 4);
  float* tk_w     = (float*)alloc((size_t)N_TOK * 2 * 4);
  int*   cnt      = (int*)alloc(64);
  int*   offs     = (int*)alloc(64);
  int*   cnt2     = (int*)alloc(64);

  hipMemsetAsync(cnt, 0, 64, stream);
  hipMemsetAsync(cnt2, 0, 64, stream);
  hipMemsetAsync(out, 0, (size_t)out_size * sizeof(float), stream);

  // fp32 -> bf16 conversions
  {
    long n4 = (long)N_TOK * DMODEL / 4;
    cvt_f32_bf16<<<(unsigned)((n4 + 255) / 256), 256, 0, stream>>>(x, xb, n4);
  }
  {
    long n4 = (long)NEXP * FFH * DMODEL / 4;
    cvt_f32_bf16<<<(unsigned)((n4 + 255) / 256), 256, 0, stream>>>(gw, gwb, n4);
    cvt_f32_bf16<<<(unsigned)((n4 + 255) / 256), 256, 0, stream>>>(uw, uwb, n4);
    cvt_f32_bf16<<<(unsigned)((n4 + 255) / 256), 256, 0, stream>>>(dw, dwb, n4);
  }

  router_k<<<N_TOK / 4, 256, 0, stream>>>(x, rw, tk_e, tk_w, cnt);
  offs_k<<<1, 64, 0, stream>>>(cnt, offs);
  scatter_k<<<N_TOK / 256, 256, 0, stream>>>(tk_e, tk_w, offs, cnt2, tok_list, w_list);

  gemm_gu_k<<<dim3(FFH / 128, ATOT / 128, NEXP), 256, 0, stream>>>(
      xb, gwb, uwb, hbuf, tok_list, cnt, offs);
  gemm_down_k<<<dim3(DMODEL / 128, ATOT / 128, NEXP), 256, 0, stream>>>(
      hbuf, dwb, out, tok_list, w_list, cnt, offs);
}

// Round 2
// 2122.843 us; speedup vs baseline: 1.0871x; 1.0871x over previous
//
#include <hip/hip_runtime.h>
#include <hip/hip_bf16.h>
#include <cstdint>

#define N_TOK 16384
#define DMODEL 2048
#define FFH    3072
#define NGU    (2 * FFH)   // 6144 interleaved gate/up rows
#define NEXP   8
#define ATOT   32768       // N_TOK * TOP_K

typedef __bf16 bf16;
typedef __attribute__((ext_vector_type(8))) __bf16 bf16x8;
typedef __attribute__((ext_vector_type(4))) __bf16 bf16x4;
typedef __attribute__((ext_vector_type(4))) float  f32x4;

__device__ __forceinline__ void gl_lds16(const bf16* g, void* l) {
  __builtin_amdgcn_global_load_lds(
      (const __attribute__((address_space(1))) void*)g,
      (__attribute__((address_space(3))) void*)l, 16, 0, 0);
}

// ---------------- fp32 -> bf16 conversion (vectorized) ----------------
__global__ void cvt_f32_bf16(const float* __restrict__ src, bf16* __restrict__ dst, long n4) {
  long i = (long)blockIdx.x * blockDim.x + threadIdx.x;
  if (i >= n4) return;
  const float4 v = ((const float4*)src)[i];
  bf16x4 o;
  o.x = (bf16)v.x; o.y = (bf16)v.y; o.z = (bf16)v.z; o.w = (bf16)v.w;
  ((bf16x4*)dst)[i] = o;
}

// ---------------- gate/up -> interleaved bf16 buffer ----------------
// guw row ri (0..6143): hb = ri>>6, sub = ri&63; sub<32 -> gate[hb*32+sub], else up[hb*32+sub-32]
__global__ void cvt_guw(const float* __restrict__ gw, const float* __restrict__ uw,
                        bf16* __restrict__ guw) {
  const long i = (long)blockIdx.x * 256 + threadIdx.x;   // one thread per 8 elems
  const int c8 = (int)(i & 255);                          // 2048/8 chunks
  const long rg = i >> 8;                                 // 0..8*6144-1
  const int e = (int)(rg / NGU);
  const int ri = (int)(rg - (long)e * NGU);
  const int hb = ri >> 6, sub = ri & 63;
  const float* src = (sub < 32 ? gw : uw) + ((size_t)e * FFH + hb * 32 + (sub & 31)) * DMODEL + c8 * 8;
  const float4 v0 = ((const float4*)src)[0];
  const float4 v1 = ((const float4*)src)[1];
  bf16x8 o;
  o[0] = (bf16)v0.x; o[1] = (bf16)v0.y; o[2] = (bf16)v0.z; o[3] = (bf16)v0.w;
  o[4] = (bf16)v1.x; o[5] = (bf16)v1.y; o[6] = (bf16)v1.z; o[7] = (bf16)v1.w;
  *(bf16x8*)(guw + rg * DMODEL + c8 * 8) = o;
}

// ---------------- router: logits, top-2, renormalized weights ----------------
__global__ void router_k(const float* __restrict__ x, const float* __restrict__ rw,
                         int* __restrict__ tk_e, float* __restrict__ tk_w,
                         int* __restrict__ cnt) {
  const int wv = threadIdx.x >> 6, lane = threadIdx.x & 63;
  const int t = blockIdx.x * 4 + wv;
  const float* xr = x + (size_t)t * DMODEL;
  float acc[NEXP];
#pragma unroll
  for (int e = 0; e < NEXP; ++e) acc[e] = 0.f;
  for (int k = lane; k < DMODEL; k += 64) {
    const float xv = xr[k];
#pragma unroll
    for (int e = 0; e < NEXP; ++e) acc[e] = fmaf(xv, rw[e * DMODEL + k], acc[e]);
  }
#pragma unroll
  for (int e = 0; e < NEXP; ++e) {
#pragma unroll
    for (int o = 32; o; o >>= 1) acc[e] += __shfl_xor(acc[e], o, 64);
  }
  if (lane == 0) {
    int e0 = 0; float v0 = acc[0];
#pragma unroll
    for (int e = 1; e < NEXP; ++e) if (acc[e] > v0) { v0 = acc[e]; e0 = e; }
    int e1 = -1; float v1 = -1e30f;
#pragma unroll
    for (int e = 0; e < NEXP; ++e) if (e != e0 && acc[e] > v1) { v1 = acc[e]; e1 = e; }
    const float w0 = 1.f / (1.f + __expf(v1 - v0));
    tk_e[t * 2] = e0; tk_e[t * 2 + 1] = e1;
    tk_w[t * 2] = w0; tk_w[t * 2 + 1] = 1.f - w0;
    atomicAdd(&cnt[e0], 1); atomicAdd(&cnt[e1], 1);
  }
}

__global__ void offs_k(const int* __restrict__ cnt, int* __restrict__ offs) {
  if (threadIdx.x == 0) {
    int o = 0;
    for (int e = 0; e < NEXP; ++e) { offs[e] = o; o += cnt[e]; }
  }
}

// scatter token ids into per-expert lists; record assignment index per (token,k)
__global__ void scatter_k(const int* __restrict__ tk_e, const float* __restrict__ tk_w,
                          const int* __restrict__ offs, int* __restrict__ cnt2,
                          int* __restrict__ tok_list, float* __restrict__ w_list,
                          int* __restrict__ aidx) {
  const int t = blockIdx.x * 256 + threadIdx.x;
  if (t >= N_TOK) return;
#pragma unroll
  for (int k = 0; k < 2; ++k) {
    const int e = tk_e[t * 2 + k];
    const int p = atomicAdd(&cnt2[e], 1);
    const int a = offs[e] + p;
    tok_list[a] = t;
    w_list[a] = tk_w[t * 2 + k];
    aidx[t * 2 + k] = a;
  }
}

// ---------------- 256x256x32 3-buffer 4-phase MFMA GEMM ----------------
// EPI=0: A = xb gathered by tok_list, B = guw (N=6144), epilogue silu(g)*u -> hbuf bf16
// EPI=1: A = hbuf (assignment rows), B = dwb (N=2048), epilogue -> ybuf fp32
template<int EPI>
__global__ __launch_bounds__(512, 2) void gemm_moe(
    const bf16* __restrict__ A, const bf16* __restrict__ B,
    bf16* __restrict__ hbuf, float* __restrict__ ybuf,
    const int* __restrict__ tok_list, const int* __restrict__ cnt,
    const int* __restrict__ offs) {
  constexpr int KD = EPI ? FFH : DMODEL;   // K length
  constexpr int NT = KD / 32;              // K-tiles
  constexpr int BROWS = EPI ? DMODEL : NGU;

  const int e = blockIdx.z;
  const int cn = cnt[e];
  const int mbase = blockIdx.y * 256;
  if (mbase >= cn) return;
  const int offE = offs[e];
  const int nbase = blockIdx.x * 256;

  __shared__ char lds[98304];              // A: 3x16KB @0, B: 3x16KB @49152
  char* const ldsA = lds;
  char* const ldsB = lds + 49152;

  const int tid = threadIdx.x;
  const int wv = tid >> 6, lane = tid & 63;
  const int wr = wv >> 2, wc = wv & 3;

  // ---- staging source (per-lane, pre-swizzled chunk) ----
  const int sr = tid >> 2;                            // 0..127 row in half
  const int swz8 = ((tid & 3) ^ (sr & 3)) * 8;        // swizzled 16B-chunk, in elems
  const bf16* pA[2]; const bf16* pB[2];
  if (EPI == 0) {
    const int t0 = tok_list[offE + min(mbase + sr, cn - 1)];
    const int t1 = tok_list[offE + min(mbase + 128 + sr, cn - 1)];
    pA[0] = A + (size_t)t0 * KD + swz8;
    pA[1] = A + (size_t)t1 * KD + swz8;
  } else {
    const int a0 = offE + min(mbase + sr, cn - 1);
    const int a1 = offE + min(mbase + 128 + sr, cn - 1);
    pA[0] = A + (size_t)a0 * KD + swz8;
    pA[1] = A + (size_t)a1 * KD + swz8;
  }
  pB[0] = B + ((size_t)e * BROWS + nbase + sr) * KD + swz8;
  pB[1] = B + ((size_t)e * BROWS + nbase + 128 + sr) * KD + swz8;

  const int stageDst = wv * 1024;                     // + half*8192 + buf*16384

  // ---- ds_read addresses (swizzled to match source pre-swizzle) ----
  const int rswz = ((lane >> 4) ^ (lane & 3)) * 16;               // byte
  const int arow = (wr * 128 + (lane & 15)) * 64 + rswz;          // + mf*1024
  const int brow = (wc * 64 + (lane & 15)) * 64 + rswz;           // + nf*1024

  const f32x4 zero = {0.f, 0.f, 0.f, 0.f};
  f32x4 acc[8][4];
#pragma unroll
  for (int i = 0; i < 8; ++i)
#pragma unroll
    for (int j = 0; j < 4; ++j) acc[i][j] = zero;

  auto stage_half = [&](int buf, int q, int kt) {
    const int k8 = kt * 32;
    if (q < 2) gl_lds16(pA[q] + k8, ldsA + buf * 16384 + q * 8192 + stageDst);
    else       gl_lds16(pB[q - 2] + k8, ldsB + buf * 16384 + (q - 2) * 8192 + stageDst);
  };

  // prologue: stage tiles 0 and 1
#pragma unroll
  for (int q = 0; q < 4; ++q) stage_half(0, q, 0);
#pragma unroll
  for (int q = 0; q < 4; ++q) stage_half(1, q, 1);
  asm volatile("s_waitcnt vmcnt(4)" ::: "memory");   // tile 0 landed
  __builtin_amdgcn_s_barrier();
  asm volatile("" ::: "memory");

  int cb = 0;
  for (int kt = 0; kt < NT; ++kt) {
    const int sb = (cb + 2 >= 3) ? cb - 1 : cb + 2;  // (cb+2)%3 = buffer freed last tile
    const char* cA = ldsA + cb * 16384;
    const char* cB = ldsB + cb * 16384;
    bf16x8 bfr[4];
#pragma unroll
    for (int q = 0; q < 4; ++q) {
      const bf16x8 a0 = *(const bf16x8*)(cA + (q * 2) * 1024 + arow);
      const bf16x8 a1 = *(const bf16x8*)(cA + (q * 2 + 1) * 1024 + arow);
      if (q == 0) {
#pragma unroll
        for (int nf = 0; nf < 4; ++nf)
          bfr[nf] = *(const bf16x8*)(cB + nf * 1024 + brow);
      }
      if (kt + 2 < NT) stage_half(sb, q, kt + 2);
      asm volatile("" ::: "memory");
      __builtin_amdgcn_s_barrier();
      asm volatile("" ::: "memory");
      __builtin_amdgcn_s_setprio(1);
#pragma unroll
      for (int nf = 0; nf < 4; ++nf) {
        acc[q * 2][nf]     = __builtin_amdgcn_mfma_f32_16x16x32_bf16(a0, bfr[nf], acc[q * 2][nf], 0, 0, 0);
        acc[q * 2 + 1][nf] = __builtin_amdgcn_mfma_f32_16x16x32_bf16(a1, bfr[nf], acc[q * 2 + 1][nf], 0, 0, 0);
      }
      __builtin_amdgcn_s_setprio(0);
      if (q == 3) {
        if (kt + 2 < NT) { asm volatile("s_waitcnt vmcnt(4)" ::: "memory"); }
        else             { asm volatile("s_waitcnt vmcnt(0)" ::: "memory"); }
      }
      asm volatile("" ::: "memory");
      __builtin_amdgcn_s_barrier();
      asm volatile("" ::: "memory");
    }
    cb = (cb + 1 == 3) ? 0 : cb + 1;
  }

  // ---- epilogue (C/D layout: col = lane&15, row = (lane>>4)*4 + j) ----
  const int col = lane & 15;
  const int rb = mbase + wr * 128 + (lane >> 4) * 4;
  if (EPI == 0) {
    const int hb32 = ((nbase + wc * 64) >> 6) * 32;  // h base for this wave's 64-col stripe
#pragma unroll
    for (int mi = 0; mi < 8; ++mi)
#pragma unroll
      for (int j = 0; j < 4; ++j) {
        const int row = rb + mi * 16 + j;
        if (row < cn) {
          bf16* hr = hbuf + (size_t)(offE + row) * FFH + hb32 + col;
#pragma unroll
          for (int k = 0; k < 2; ++k) {
            const float g = acc[mi][k][j], u = acc[mi][k + 2][j];
            hr[k * 16] = (bf16)(g / (1.f + __expf(-g)) * u);
          }
        }
      }
  } else {
#pragma unroll
    for (int mi = 0; mi < 8; ++mi)
#pragma unroll
      for (int j = 0; j < 4; ++j) {
        const int row = rb + mi * 16 + j;
        if (row < cn) {
          float* yr = ybuf + (size_t)(offE + row) * DMODEL + nbase + wc * 64 + col;
#pragma unroll
          for (int nf = 0; nf < 4; ++nf) yr[nf * 16] = acc[mi][nf][j];
        }
      }
  }
}

// ---------------- final combine: out[t] = w0*y[a0] + w1*y[a1] ----------------
__global__ void combine_k(const float* __restrict__ ybuf, const int* __restrict__ aidx,
                          const float* __restrict__ tk_w, float* __restrict__ out) {
  const int i = blockIdx.x * 256 + threadIdx.x;   // N_TOK*512 threads, 4 cols each
  const int t = i >> 9, c = i & 511;
  const int a0 = aidx[t * 2], a1 = aidx[t * 2 + 1];
  const float w0 = tk_w[t * 2], w1 = tk_w[t * 2 + 1];
  const float4 v0 = ((const float4*)(ybuf + (size_t)a0 * DMODEL))[c];
  const float4 v1 = ((const float4*)(ybuf + (size_t)a1 * DMODEL))[c];
  float4 o;
  o.x = w0 * v0.x + w1 * v1.x;
  o.y = w0 * v0.y + w1 * v1.y;
  o.z = w0 * v0.z + w1 * v1.z;
  o.w = w0 * v0.w + w1 * v1.w;
  ((float4*)(out + (size_t)t * DMODEL))[c] = o;
}

extern "C" void kernel_launch(void* const* d_in, const int* in_sizes, int n_in,
                              void* d_out, int out_size, void* d_ws, size_t ws_size,
                              hipStream_t stream) {
  const float* x  = (const float*)d_in[0];
  const float* rw = (const float*)d_in[1];
  const float* gw = (const float*)d_in[2];
  const float* uw = (const float*)d_in[3];
  const float* dw = (const float*)d_in[4];
  float* out = (float*)d_out;

  char* ws = (char*)d_ws;
  size_t o = 0;
  auto alloc = [&](size_t bytes) {
    void* p = ws + o;
    o = (o + bytes + 255) & ~(size_t)255;
    return p;
  };

  const size_t guw_bytes  = (size_t)NEXP * NGU * DMODEL * 2;          // 201.3 MB
  const size_t ybuf_bytes = (size_t)(ATOT + 256) * DMODEL * 4;        // 270.5 MB
  bf16*  xb       = (bf16*)alloc((size_t)N_TOK * DMODEL * 2);         // 67 MB
  void*  uni      = alloc(ybuf_bytes > guw_bytes ? ybuf_bytes : guw_bytes);
  bf16*  guw      = (bf16*)uni;     // live: cvt..gemm1
  float* ybuf     = (float*)uni;    // live: gemm2..combine (gemm1 done with guw by then)
  bf16*  dwb      = (bf16*)alloc((size_t)NEXP * DMODEL * FFH * 2);    // 100.7 MB
  bf16*  hbuf     = (bf16*)alloc((size_t)(ATOT + 256) * FFH * 2);     // 202.9 MB
  int*   tok_list = (int*)alloc((ATOT + 256) * 4);
  float* w_list   = (float*)alloc((ATOT + 256) * 4);
  int*   tk_e     = (int*)alloc((size_t)N_TOK * 2 * 4);
  float* tk_w     = (float*)alloc((size_t)N_TOK * 2 * 4);
  int*   aidx     = (int*)alloc((size_t)N_TOK * 2 * 4);
  int*   cnt      = (int*)alloc(64);
  int*   offs     = (int*)alloc(64);
  int*   cnt2     = (int*)alloc(64);

  hipMemsetAsync(cnt, 0, 64, stream);
  hipMemsetAsync(cnt2, 0, 64, stream);

  // conversions
  {
    long n4 = (long)N_TOK * DMODEL / 4;
    cvt_f32_bf16<<<(unsigned)(n4 / 256), 256, 0, stream>>>(x, xb, n4);
  }
  cvt_guw<<<(unsigned)((long)NEXP * NGU * DMODEL / 8 / 256), 256, 0, stream>>>(gw, uw, guw);
  {
    long n4 = (long)NEXP * DMODEL * FFH / 4;
    cvt_f32_bf16<<<(unsigned)(n4 / 256), 256, 0, stream>>>(dw, dwb, n4);
  }

  // routing
  router_k<<<N_TOK / 4, 256, 0, stream>>>(x, rw, tk_e, tk_w, cnt);
  offs_k<<<1, 64, 0, stream>>>(cnt, offs);
  scatter_k<<<N_TOK / 256, 256, 0, stream>>>(tk_e, tk_w, offs, cnt2, tok_list, w_list, aidx);

  // expert GEMMs (m-grid covers worst case cn=16384 -> 64 tiles; empty blocks exit)
  gemm_moe<0><<<dim3(NGU / 256, 64, NEXP), 512, 0, stream>>>(
      xb, guw, hbuf, nullptr, tok_list, cnt, offs);
  gemm_moe<1><<<dim3(DMODEL / 256, 64, NEXP), 512, 0, stream>>>(
      hbuf, dwb, nullptr, ybuf, tok_list, cnt, offs);

  // combine (fully overwrites d_out every call)
  combine_k<<<N_TOK * 512 / 256, 256, 0, stream>>>(ybuf, aidx, tk_w, out);
}

// Round 3
// 2058.907 us; speedup vs baseline: 1.1209x; 1.0311x over previous
//
#include <hip/hip_runtime.h>
#include <hip/hip_bf16.h>
#include <cstdint>

#define N_TOK 16384
#define DMODEL 2048
#define FFH    3072
#define NGU    (2 * FFH)   // 6144 interleaved gate/up rows
#define NEXP   8
#define ATOT   32768       // N_TOK * TOP_K

typedef __bf16 bf16;
typedef __attribute__((ext_vector_type(8))) __bf16 bf16x8;
typedef __attribute__((ext_vector_type(4))) __bf16 bf16x4;
typedef __attribute__((ext_vector_type(4))) float  f32x4;

__device__ __forceinline__ void gl_lds16(const bf16* g, void* l) {
  __builtin_amdgcn_global_load_lds(
      (const __attribute__((address_space(1))) void*)g,
      (__attribute__((address_space(3))) void*)l, 16, 0, 0);
}

// ---------------- fp32 -> bf16 conversion (vectorized) ----------------
__global__ void cvt_f32_bf16(const float* __restrict__ src, bf16* __restrict__ dst, long n4) {
  long i = (long)blockIdx.x * blockDim.x + threadIdx.x;
  if (i >= n4) return;
  const float4 v = ((const float4*)src)[i];
  bf16x4 o;
  o.x = (bf16)v.x; o.y = (bf16)v.y; o.z = (bf16)v.z; o.w = (bf16)v.w;
  ((bf16x4*)dst)[i] = o;
}

// ---------------- gate/up -> interleaved bf16 buffer ----------------
// guw row ri (0..6143): hb = ri>>6, sub = ri&63; sub<32 -> gate[hb*32+sub], else up[hb*32+sub-32]
__global__ void cvt_guw(const float* __restrict__ gw, const float* __restrict__ uw,
                        bf16* __restrict__ guw) {
  const long i = (long)blockIdx.x * 256 + threadIdx.x;   // one thread per 8 elems
  const int c8 = (int)(i & 255);                          // 2048/8 chunks
  const long rg = i >> 8;                                 // 0..8*6144-1
  const int e = (int)(rg / NGU);
  const int ri = (int)(rg - (long)e * NGU);
  const int hb = ri >> 6, sub = ri & 63;
  const float* src = (sub < 32 ? gw : uw) + ((size_t)e * FFH + hb * 32 + (sub & 31)) * DMODEL + c8 * 8;
  const float4 v0 = ((const float4*)src)[0];
  const float4 v1 = ((const float4*)src)[1];
  bf16x8 o;
  o[0] = (bf16)v0.x; o[1] = (bf16)v0.y; o[2] = (bf16)v0.z; o[3] = (bf16)v0.w;
  o[4] = (bf16)v1.x; o[5] = (bf16)v1.y; o[6] = (bf16)v1.z; o[7] = (bf16)v1.w;
  *(bf16x8*)(guw + rg * DMODEL + c8 * 8) = o;
}

// ---------------- router: logits, top-2, renormalized weights ----------------
__global__ void router_k(const float* __restrict__ x, const float* __restrict__ rw,
                         int* __restrict__ tk_e, float* __restrict__ tk_w,
                         int* __restrict__ cnt) {
  const int wv = threadIdx.x >> 6, lane = threadIdx.x & 63;
  const int t = blockIdx.x * 4 + wv;
  const float* xr = x + (size_t)t * DMODEL;
  float acc[NEXP];
#pragma unroll
  for (int e = 0; e < NEXP; ++e) acc[e] = 0.f;
  for (int k = lane; k < DMODEL; k += 64) {
    const float xv = xr[k];
#pragma unroll
    for (int e = 0; e < NEXP; ++e) acc[e] = fmaf(xv, rw[e * DMODEL + k], acc[e]);
  }
#pragma unroll
  for (int e = 0; e < NEXP; ++e) {
#pragma unroll
    for (int o = 32; o; o >>= 1) acc[e] += __shfl_xor(acc[e], o, 64);
  }
  if (lane == 0) {
    int e0 = 0; float v0 = acc[0];
#pragma unroll
    for (int e = 1; e < NEXP; ++e) if (acc[e] > v0) { v0 = acc[e]; e0 = e; }
    int e1 = -1; float v1 = -1e30f;
#pragma unroll
    for (int e = 0; e < NEXP; ++e) if (e != e0 && acc[e] > v1) { v1 = acc[e]; e1 = e; }
    const float w0 = 1.f / (1.f + __expf(v1 - v0));
    tk_e[t * 2] = e0; tk_e[t * 2 + 1] = e1;
    tk_w[t * 2] = w0; tk_w[t * 2 + 1] = 1.f - w0;
    atomicAdd(&cnt[e0], 1); atomicAdd(&cnt[e1], 1);
  }
}

__global__ void offs_k(const int* __restrict__ cnt, int* __restrict__ offs) {
  if (threadIdx.x == 0) {
    int o = 0;
    for (int e = 0; e < NEXP; ++e) { offs[e] = o; o += cnt[e]; }
  }
}

// scatter token ids into per-expert lists; record assignment index per (token,k)
__global__ void scatter_k(const int* __restrict__ tk_e, const float* __restrict__ tk_w,
                          const int* __restrict__ offs, int* __restrict__ cnt2,
                          int* __restrict__ tok_list, float* __restrict__ w_list,
                          int* __restrict__ aidx) {
  const int t = blockIdx.x * 256 + threadIdx.x;
  if (t >= N_TOK) return;
#pragma unroll
  for (int k = 0; k < 2; ++k) {
    const int e = tk_e[t * 2 + k];
    const int p = atomicAdd(&cnt2[e], 1);
    const int a = offs[e] + p;
    tok_list[a] = t;
    w_list[a] = tk_w[t * 2 + k];
    aidx[t * 2 + k] = a;
  }
}

// ---------------- 256x256x32 3-buffer 4-phase MFMA GEMM ----------------
// EPI=0: A = xb gathered by tok_list, B = guw (N=6144), epilogue silu(g)*u -> hbuf bf16
// EPI=1: A = hbuf (assignment rows), B = dwb (N=2048), epilogue -> ybuf fp32
// LDS swizzle: rows are 64B (half a 128B bank line), so the bank slot of a 16B
// chunk is ((row&1)<<2)|chunk. Swizzle with row bits ABOVE parity:
// chunk ^= (row>>1)&3 -> (row&1, xor-field) bijective over row%8 -> 2 lanes/slot
// (distinct addrs) per 16-lane group = conflict-free b128 service.
template<int EPI>
__global__ __launch_bounds__(512, 2) void gemm_moe(
    const bf16* __restrict__ A, const bf16* __restrict__ B,
    bf16* __restrict__ hbuf, float* __restrict__ ybuf,
    const int* __restrict__ tok_list, const int* __restrict__ cnt,
    const int* __restrict__ offs) {
  constexpr int KD = EPI ? FFH : DMODEL;   // K length
  constexpr int NT = KD / 32;              // K-tiles
  constexpr int BROWS = EPI ? DMODEL : NGU;

  const int e = blockIdx.z;
  const int cn = cnt[e];
  const int mbase = blockIdx.y * 256;
  if (mbase >= cn) return;
  const int offE = offs[e];
  const int nbase = blockIdx.x * 256;

  __shared__ char lds[98304];              // A: 3x16KB @0, B: 3x16KB @49152
  char* const ldsA = lds;
  char* const ldsB = lds + 49152;

  const int tid = threadIdx.x;
  const int wv = tid >> 6, lane = tid & 63;
  const int wr = wv >> 2, wc = wv & 3;

  // ---- staging source (per-lane, pre-swizzled chunk) ----
  const int sr = tid >> 2;                            // 0..127 row in half
  const int swz8 = ((tid & 3) ^ ((tid >> 3) & 3)) * 8;  // chunk ^ (row>>1)&3, in elems
  const bf16* pA[2]; const bf16* pB[2];
  if (EPI == 0) {
    const int t0 = tok_list[offE + min(mbase + sr, cn - 1)];
    const int t1 = tok_list[offE + min(mbase + 128 + sr, cn - 1)];
    pA[0] = A + (size_t)t0 * KD + swz8;
    pA[1] = A + (size_t)t1 * KD + swz8;
  } else {
    const int a0 = offE + min(mbase + sr, cn - 1);
    const int a1 = offE + min(mbase + 128 + sr, cn - 1);
    pA[0] = A + (size_t)a0 * KD + swz8;
    pA[1] = A + (size_t)a1 * KD + swz8;
  }
  pB[0] = B + ((size_t)e * BROWS + nbase + sr) * KD + swz8;
  pB[1] = B + ((size_t)e * BROWS + nbase + 128 + sr) * KD + swz8;

  const int stageDst = wv * 1024;                     // + half*8192 + buf*16384

  // ---- ds_read addresses (swizzled to match source pre-swizzle) ----
  const int rswz = ((lane >> 4) ^ ((lane >> 1) & 3)) * 16;        // byte
  const int arow = (wr * 128 + (lane & 15)) * 64 + rswz;          // + mf*1024
  const int brow = (wc * 64 + (lane & 15)) * 64 + rswz;           // + nf*1024

  const f32x4 zero = {0.f, 0.f, 0.f, 0.f};
  f32x4 acc[8][4];
#pragma unroll
  for (int i = 0; i < 8; ++i)
#pragma unroll
    for (int j = 0; j < 4; ++j) acc[i][j] = zero;

  auto stage_half = [&](int buf, int q, int kt) {
    const int k8 = kt * 32;
    if (q < 2) gl_lds16(pA[q] + k8, ldsA + buf * 16384 + q * 8192 + stageDst);
    else       gl_lds16(pB[q - 2] + k8, ldsB + buf * 16384 + (q - 2) * 8192 + stageDst);
  };

  // prologue: stage tiles 0 and 1
#pragma unroll
  for (int q = 0; q < 4; ++q) stage_half(0, q, 0);
#pragma unroll
  for (int q = 0; q < 4; ++q) stage_half(1, q, 1);
  asm volatile("s_waitcnt vmcnt(4)" ::: "memory");   // tile 0 landed
  __builtin_amdgcn_s_barrier();
  asm volatile("" ::: "memory");

  int cb = 0;
  for (int kt = 0; kt < NT; ++kt) {
    const int sb = (cb + 2 >= 3) ? cb - 1 : cb + 2;  // (cb+2)%3 = buffer freed last tile
    const char* cA = ldsA + cb * 16384;
    const char* cB = ldsB + cb * 16384;
    bf16x8 bfr[4];
#pragma unroll
    for (int q = 0; q < 4; ++q) {
      const bf16x8 a0 = *(const bf16x8*)(cA + (q * 2) * 1024 + arow);
      const bf16x8 a1 = *(const bf16x8*)(cA + (q * 2 + 1) * 1024 + arow);
      if (q == 0) {
#pragma unroll
        for (int nf = 0; nf < 4; ++nf)
          bfr[nf] = *(const bf16x8*)(cB + nf * 1024 + brow);
      }
      if (kt + 2 < NT) stage_half(sb, q, kt + 2);
      asm volatile("" ::: "memory");
      __builtin_amdgcn_s_barrier();
      asm volatile("" ::: "memory");
      __builtin_amdgcn_s_setprio(1);
#pragma unroll
      for (int nf = 0; nf < 4; ++nf) {
        acc[q * 2][nf]     = __builtin_amdgcn_mfma_f32_16x16x32_bf16(a0, bfr[nf], acc[q * 2][nf], 0, 0, 0);
        acc[q * 2 + 1][nf] = __builtin_amdgcn_mfma_f32_16x16x32_bf16(a1, bfr[nf], acc[q * 2 + 1][nf], 0, 0, 0);
      }
      __builtin_amdgcn_s_setprio(0);
      if (q == 3) {
        if (kt + 2 < NT) { asm volatile("s_waitcnt vmcnt(4)" ::: "memory"); }
        else             { asm volatile("s_waitcnt vmcnt(0)" ::: "memory"); }
      }
      asm volatile("" ::: "memory");
      __builtin_amdgcn_s_barrier();
      asm volatile("" ::: "memory");
    }
    cb = (cb + 1 == 3) ? 0 : cb + 1;
  }

  // ---- epilogue (C/D layout: col = lane&15, row = (lane>>4)*4 + j) ----
  const int col = lane & 15;
  const int rb = mbase + wr * 128 + (lane >> 4) * 4;
  if (EPI == 0) {
    const int hb32 = ((nbase + wc * 64) >> 6) * 32;  // h base for this wave's 64-col stripe
#pragma unroll
    for (int mi = 0; mi < 8; ++mi)
#pragma unroll
      for (int j = 0; j < 4; ++j) {
        const int row = rb + mi * 16 + j;
        if (row < cn) {
          bf16* hr = hbuf + (size_t)(offE + row) * FFH + hb32 + col;
#pragma unroll
          for (int k = 0; k < 2; ++k) {
            const float g = acc[mi][k][j], u = acc[mi][k + 2][j];
            hr[k * 16] = (bf16)(g / (1.f + __expf(-g)) * u);
          }
        }
      }
  } else {
#pragma unroll
    for (int mi = 0; mi < 8; ++mi)
#pragma unroll
      for (int j = 0; j < 4; ++j) {
        const int row = rb + mi * 16 + j;
        if (row < cn) {
          float* yr = ybuf + (size_t)(offE + row) * DMODEL + nbase + wc * 64 + col;
#pragma unroll
          for (int nf = 0; nf < 4; ++nf) yr[nf * 16] = acc[mi][nf][j];
        }
      }
  }
}

// ---------------- final combine: out[t] = w0*y[a0] + w1*y[a1] ----------------
__global__ void combine_k(const float* __restrict__ ybuf, const int* __restrict__ aidx,
                          const float* __restrict__ tk_w, float* __restrict__ out) {
  const int i = blockIdx.x * 256 + threadIdx.x;   // N_TOK*512 threads, 4 cols each
  const int t = i >> 9, c = i & 511;
  const int a0 = aidx[t * 2], a1 = aidx[t * 2 + 1];
  const float w0 = tk_w[t * 2], w1 = tk_w[t * 2 + 1];
  const float4 v0 = ((const float4*)(ybuf + (size_t)a0 * DMODEL))[c];
  const float4 v1 = ((const float4*)(ybuf + (size_t)a1 * DMODEL))[c];
  float4 o;
  o.x = w0 * v0.x + w1 * v1.x;
  o.y = w0 * v0.y + w1 * v1.y;
  o.z = w0 * v0.z + w1 * v1.z;
  o.w = w0 * v0.w + w1 * v1.w;
  ((float4*)(out + (size_t)t * DMODEL))[c] = o;
}

extern "C" void kernel_launch(void* const* d_in, const int* in_sizes, int n_in,
                              void* d_out, int out_size, void* d_ws, size_t ws_size,
                              hipStream_t stream) {
  const float* x  = (const float*)d_in[0];
  const float* rw = (const float*)d_in[1];
  const float* gw = (const float*)d_in[2];
  const float* uw = (const float*)d_in[3];
  const float* dw = (const float*)d_in[4];
  float* out = (float*)d_out;

  char* ws = (char*)d_ws;
  size_t o = 0;
  auto alloc = [&](size_t bytes) {
    void* p = ws + o;
    o = (o + bytes + 255) & ~(size_t)255;
    return p;
  };

  const size_t guw_bytes  = (size_t)NEXP * NGU * DMODEL * 2;          // 201.3 MB
  const size_t ybuf_bytes = (size_t)(ATOT + 256) * DMODEL * 4;        // 270.5 MB
  bf16*  xb       = (bf16*)alloc((size_t)N_TOK * DMODEL * 2);         // 67 MB
  void*  uni      = alloc(ybuf_bytes > guw_bytes ? ybuf_bytes : guw_bytes);
  bf16*  guw      = (bf16*)uni;     // live: cvt..gemm1
  float* ybuf     = (float*)uni;    // live: gemm2..combine (gemm1 done with guw by then)
  bf16*  dwb      = (bf16*)alloc((size_t)NEXP * DMODEL * FFH * 2);    // 100.7 MB
  bf16*  hbuf     = (bf16*)alloc((size_t)(ATOT + 256) * FFH * 2);     // 202.9 MB
  int*   tok_list = (int*)alloc((ATOT + 256) * 4);
  float* w_list   = (float*)alloc((ATOT + 256) * 4);
  int*   tk_e     = (int*)alloc((size_t)N_TOK * 2 * 4);
  float* tk_w     = (float*)alloc((size_t)N_TOK * 2 * 4);
  int*   aidx     = (int*)alloc((size_t)N_TOK * 2 * 4);
  int*   cnt      = (int*)alloc(64);
  int*   offs     = (int*)alloc(64);
  int*   cnt2     = (int*)alloc(64);

  hipMemsetAsync(cnt, 0, 64, stream);
  hipMemsetAsync(cnt2, 0, 64, stream);

  // conversions
  {
    long n4 = (long)N_TOK * DMODEL / 4;
    cvt_f32_bf16<<<(unsigned)(n4 / 256), 256, 0, stream>>>(x, xb, n4);
  }
  cvt_guw<<<(unsigned)((long)NEXP * NGU * DMODEL / 8 / 256), 256, 0, stream>>>(gw, uw, guw);
  {
    long n4 = (long)NEXP * DMODEL * FFH / 4;
    cvt_f32_bf16<<<(unsigned)(n4 / 256), 256, 0, stream>>>(dw, dwb, n4);
  }

  // routing
  router_k<<<N_TOK / 4, 256, 0, stream>>>(x, rw, tk_e, tk_w, cnt);
  offs_k<<<1, 64, 0, stream>>>(cnt, offs);
  scatter_k<<<N_TOK / 256, 256, 0, stream>>>(tk_e, tk_w, offs, cnt2, tok_list, w_list, aidx);

  // expert GEMMs (m-grid covers worst case cn=16384 -> 64 tiles; empty blocks exit)
  gemm_moe<0><<<dim3(NGU / 256, 64, NEXP), 512, 0, stream>>>(
      xb, guw, hbuf, nullptr, tok_list, cnt, offs);
  gemm_moe<1><<<dim3(DMODEL / 256, 64, NEXP), 512, 0, stream>>>(
      hbuf, dwb, nullptr, ybuf, tok_list, cnt, offs);

  // combine (fully overwrites d_out every call)
  combine_k<<<N_TOK * 512 / 256, 256, 0, stream>>>(ybuf, aidx, tk_w, out);
}

// Round 4
// 1999.122 us; speedup vs baseline: 1.1544x; 1.0299x over previous
//
#include <hip/hip_runtime.h>
#include <hip/hip_bf16.h>
#include <cstdint>

#define N_TOK 16384
#define DMODEL 2048
#define FFH    3072
#define NGU    (2 * FFH)   // 6144 interleaved gate/up rows
#define NEXP   8
#define ATOT   32768       // N_TOK * TOP_K

typedef __bf16 bf16;
typedef __attribute__((ext_vector_type(8))) __bf16 bf16x8;
typedef __attribute__((ext_vector_type(4))) __bf16 bf16x4;
typedef __attribute__((ext_vector_type(4))) float  f32x4;

__device__ __forceinline__ void gl_lds16(const bf16* g, void* l) {
  __builtin_amdgcn_global_load_lds(
      (const __attribute__((address_space(1))) void*)g,
      (__attribute__((address_space(3))) void*)l, 16, 0, 0);
}

// ---------------- fp32 -> bf16 conversion (vectorized) ----------------
__global__ void cvt_f32_bf16(const float* __restrict__ src, bf16* __restrict__ dst, long n4) {
  long i = (long)blockIdx.x * blockDim.x + threadIdx.x;
  if (i >= n4) return;
  const float4 v = ((const float4*)src)[i];
  bf16x4 o;
  o.x = (bf16)v.x; o.y = (bf16)v.y; o.z = (bf16)v.z; o.w = (bf16)v.w;
  ((bf16x4*)dst)[i] = o;
}

// ---------------- gate/up -> interleaved bf16 buffer ----------------
// guw row ri (0..6143): hb = ri>>6, sub = ri&63; sub<32 -> gate[hb*32+sub], else up[hb*32+sub-32]
__global__ void cvt_guw(const float* __restrict__ gw, const float* __restrict__ uw,
                        bf16* __restrict__ guw) {
  const long i = (long)blockIdx.x * 256 + threadIdx.x;   // one thread per 8 elems
  const int c8 = (int)(i & 255);                          // 2048/8 chunks
  const long rg = i >> 8;                                 // 0..8*6144-1
  const int e = (int)(rg / NGU);
  const int ri = (int)(rg - (long)e * NGU);
  const int hb = ri >> 6, sub = ri & 63;
  const float* src = (sub < 32 ? gw : uw) + ((size_t)e * FFH + hb * 32 + (sub & 31)) * DMODEL + c8 * 8;
  const float4 v0 = ((const float4*)src)[0];
  const float4 v1 = ((const float4*)src)[1];
  bf16x8 o;
  o[0] = (bf16)v0.x; o[1] = (bf16)v0.y; o[2] = (bf16)v0.z; o[3] = (bf16)v0.w;
  o[4] = (bf16)v1.x; o[5] = (bf16)v1.y; o[6] = (bf16)v1.z; o[7] = (bf16)v1.w;
  *(bf16x8*)(guw + rg * DMODEL + c8 * 8) = o;
}

// ---------------- router: logits, top-2, renormalized weights ----------------
__global__ void router_k(const float* __restrict__ x, const float* __restrict__ rw,
                         int* __restrict__ tk_e, float* __restrict__ tk_w,
                         int* __restrict__ cnt) {
  const int wv = threadIdx.x >> 6, lane = threadIdx.x & 63;
  const int t = blockIdx.x * 4 + wv;
  const float* xr = x + (size_t)t * DMODEL;
  float acc[NEXP];
#pragma unroll
  for (int e = 0; e < NEXP; ++e) acc[e] = 0.f;
  for (int k = lane; k < DMODEL; k += 64) {
    const float xv = xr[k];
#pragma unroll
    for (int e = 0; e < NEXP; ++e) acc[e] = fmaf(xv, rw[e * DMODEL + k], acc[e]);
  }
#pragma unroll
  for (int e = 0; e < NEXP; ++e) {
#pragma unroll
    for (int o = 32; o; o >>= 1) acc[e] += __shfl_xor(acc[e], o, 64);
  }
  if (lane == 0) {
    int e0 = 0; float v0 = acc[0];
#pragma unroll
    for (int e = 1; e < NEXP; ++e) if (acc[e] > v0) { v0 = acc[e]; e0 = e; }
    int e1 = -1; float v1 = -1e30f;
#pragma unroll
    for (int e = 0; e < NEXP; ++e) if (e != e0 && acc[e] > v1) { v1 = acc[e]; e1 = e; }
    const float w0 = 1.f / (1.f + __expf(v1 - v0));
    tk_e[t * 2] = e0; tk_e[t * 2 + 1] = e1;
    tk_w[t * 2] = w0; tk_w[t * 2 + 1] = 1.f - w0;
    atomicAdd(&cnt[e0], 1); atomicAdd(&cnt[e1], 1);
  }
}

__global__ void offs_k(const int* __restrict__ cnt, int* __restrict__ offs) {
  if (threadIdx.x == 0) {
    int o = 0;
    for (int e = 0; e < NEXP; ++e) { offs[e] = o; o += cnt[e]; }
  }
}

// scatter token ids into per-expert lists; record assignment index per (token,k)
__global__ void scatter_k(const int* __restrict__ tk_e, const float* __restrict__ tk_w,
                          const int* __restrict__ offs, int* __restrict__ cnt2,
                          int* __restrict__ tok_list, float* __restrict__ w_list,
                          int* __restrict__ aidx) {
  const int t = blockIdx.x * 256 + threadIdx.x;
  if (t >= N_TOK) return;
#pragma unroll
  for (int k = 0; k < 2; ++k) {
    const int e = tk_e[t * 2 + k];
    const int p = atomicAdd(&cnt2[e], 1);
    const int a = offs[e] + p;
    tok_list[a] = t;
    w_list[a] = tk_w[t * 2 + k];
    aidx[t * 2 + k] = a;
  }
}

// ---------------- 256x256x32 3-buffer MFMA GEMM, 1 barrier / K-tile ----------------
// EPI=0: A = xb gathered by tok_list, B = guw (N=6144), epilogue silu(g)*u -> hbuf bf16
// EPI=1: A = hbuf (assignment rows), B = dwb (N=2048), epilogue -> ybuf fp32
//
// Race invariants (3 buffers, 1 barrier + 1 counted vmcnt per iter):
//  - iter t reads cb(t), stages sb = cb(t-1) (read last iter). Stage-vs-read safety:
//    each wave's last MFMA of iter t-1 forces lgkmcnt covering ALL its ds_reads;
//    the end-of-iter barrier then orders every wave's reads before any iter-t stage.
//  - read-vs-stage safety: per-wave vmcnt(4) at end of iter t leaves only tile t+2's
//    4 loads in flight -> tile t+1 landed; barrier publishes it to all waves.
// LDS swizzle (proven r3, conflicts=0): chunk ^= (row>>1)&3 on both stage-source
// and ds_read addresses; rows are 64B so row parity is part of the bank slot.
template<int EPI>
__global__ __launch_bounds__(512, 2) void gemm_moe(
    const bf16* __restrict__ A, const bf16* __restrict__ B,
    bf16* __restrict__ hbuf, float* __restrict__ ybuf,
    const int* __restrict__ tok_list, const int* __restrict__ cnt,
    const int* __restrict__ offs) {
  constexpr int KD = EPI ? FFH : DMODEL;   // K length
  constexpr int NT = KD / 32;              // K-tiles
  constexpr int BROWS = EPI ? DMODEL : NGU;

  const int e = blockIdx.z;
  const int cn = cnt[e];
  const int mbase = blockIdx.y * 256;
  if (mbase >= cn) return;
  const int offE = offs[e];
  const int nbase = blockIdx.x * 256;

  __shared__ char lds[98304];              // A: 3x16KB @0, B: 3x16KB @49152
  char* const ldsA = lds;
  char* const ldsB = lds + 49152;

  const int tid = threadIdx.x;
  const int wv = tid >> 6, lane = tid & 63;
  const int wr = wv >> 2, wc = wv & 3;

  // ---- staging source (per-lane, pre-swizzled chunk) ----
  const int sr = tid >> 2;                              // 0..127 row in half
  const int swz8 = ((tid & 3) ^ ((tid >> 3) & 3)) * 8;  // chunk ^ (row>>1)&3, in elems
  const bf16* pA[2]; const bf16* pB[2];
  if (EPI == 0) {
    const int t0 = tok_list[offE + min(mbase + sr, cn - 1)];
    const int t1 = tok_list[offE + min(mbase + 128 + sr, cn - 1)];
    pA[0] = A + (size_t)t0 * KD + swz8;
    pA[1] = A + (size_t)t1 * KD + swz8;
  } else {
    const int a0 = offE + min(mbase + sr, cn - 1);
    const int a1 = offE + min(mbase + 128 + sr, cn - 1);
    pA[0] = A + (size_t)a0 * KD + swz8;
    pA[1] = A + (size_t)a1 * KD + swz8;
  }
  pB[0] = B + ((size_t)e * BROWS + nbase + sr) * KD + swz8;
  pB[1] = B + ((size_t)e * BROWS + nbase + 128 + sr) * KD + swz8;

  const int stageDst = wv * 1024;                       // + half*8192 + buf*16384

  // ---- ds_read addresses (swizzled to match source pre-swizzle) ----
  const int rswz = ((lane >> 4) ^ ((lane >> 1) & 3)) * 16;        // byte
  const int arow = (wr * 128 + (lane & 15)) * 64 + rswz;          // + mf*1024
  const int brow = (wc * 64 + (lane & 15)) * 64 + rswz;           // + nf*1024

  const f32x4 zero = {0.f, 0.f, 0.f, 0.f};
  f32x4 acc[8][4];
#pragma unroll
  for (int i = 0; i < 8; ++i)
#pragma unroll
    for (int j = 0; j < 4; ++j) acc[i][j] = zero;

  auto stage_half = [&](int buf, int q, int kt) {
    const int k8 = kt * 32;
    if (q < 2) gl_lds16(pA[q] + k8, ldsA + buf * 16384 + q * 8192 + stageDst);
    else       gl_lds16(pB[q - 2] + k8, ldsB + buf * 16384 + (q - 2) * 8192 + stageDst);
  };

  // prologue: stage tiles 0 and 1
#pragma unroll
  for (int q = 0; q < 4; ++q) stage_half(0, q, 0);
#pragma unroll
  for (int q = 0; q < 4; ++q) stage_half(1, q, 1);
  asm volatile("s_waitcnt vmcnt(4)" ::: "memory");   // tile 0 landed
  __builtin_amdgcn_s_barrier();
  asm volatile("" ::: "memory");

  int cb = 0;
  for (int kt = 0; kt < NT; ++kt) {
    const int sb = (cb + 2 >= 3) ? cb - 1 : cb + 2;  // buffer freed last iter
    const char* cA = ldsA + cb * 16384;
    const char* cB = ldsB + cb * 16384;

    // issue all 12 ds_reads up front (a0..a3,b0..b3 interleaved, then a4..a7);
    // compiler inserts fine-grained lgkmcnt before dependent MFMAs.
    bf16x8 a[8], b[4];
#pragma unroll
    for (int i = 0; i < 4; ++i) {
      a[i] = *(const bf16x8*)(cA + i * 1024 + arow);
      b[i] = *(const bf16x8*)(cB + i * 1024 + brow);
    }
#pragma unroll
    for (int i = 4; i < 8; ++i) a[i] = *(const bf16x8*)(cA + i * 1024 + arow);

    if (kt + 2 < NT) { stage_half(sb, 0, kt + 2); stage_half(sb, 1, kt + 2); }

    __builtin_amdgcn_s_setprio(1);
#pragma unroll
    for (int nf = 0; nf < 4; ++nf)
#pragma unroll
      for (int mi = 0; mi < 4; ++mi)
        acc[mi][nf] = __builtin_amdgcn_mfma_f32_16x16x32_bf16(a[mi], b[nf], acc[mi][nf], 0, 0, 0);
    __builtin_amdgcn_s_setprio(0);

    if (kt + 2 < NT) { stage_half(sb, 2, kt + 2); stage_half(sb, 3, kt + 2); }

    __builtin_amdgcn_s_setprio(1);
#pragma unroll
    for (int nf = 0; nf < 4; ++nf)
#pragma unroll
      for (int mi = 4; mi < 8; ++mi)
        acc[mi][nf] = __builtin_amdgcn_mfma_f32_16x16x32_bf16(a[mi], b[nf], acc[mi][nf], 0, 0, 0);
    __builtin_amdgcn_s_setprio(0);

    if (kt + 2 < NT) { asm volatile("s_waitcnt vmcnt(4)" ::: "memory"); }
    else             { asm volatile("s_waitcnt vmcnt(0)" ::: "memory"); }
    asm volatile("" ::: "memory");
    __builtin_amdgcn_s_barrier();
    asm volatile("" ::: "memory");

    cb = (cb + 1 == 3) ? 0 : cb + 1;
  }

  // ---- epilogue (C/D layout: col = lane&15, row = (lane>>4)*4 + j) ----
  const int col = lane & 15;
  const int rb = mbase + wr * 128 + (lane >> 4) * 4;
  if (EPI == 0) {
    const int hb32 = ((nbase + wc * 64) >> 6) * 32;  // h base for this wave's 64-col stripe
#pragma unroll
    for (int mi = 0; mi < 8; ++mi)
#pragma unroll
      for (int j = 0; j < 4; ++j) {
        const int row = rb + mi * 16 + j;
        if (row < cn) {
          bf16* hr = hbuf + (size_t)(offE + row) * FFH + hb32 + col;
#pragma unroll
          for (int k = 0; k < 2; ++k) {
            const float g = acc[mi][k][j], u = acc[mi][k + 2][j];
            hr[k * 16] = (bf16)(g / (1.f + __expf(-g)) * u);
          }
        }
      }
  } else {
#pragma unroll
    for (int mi = 0; mi < 8; ++mi)
#pragma unroll
      for (int j = 0; j < 4; ++j) {
        const int row = rb + mi * 16 + j;
        if (row < cn) {
          float* yr = ybuf + (size_t)(offE + row) * DMODEL + nbase + wc * 64 + col;
#pragma unroll
          for (int nf = 0; nf < 4; ++nf) yr[nf * 16] = acc[mi][nf][j];
        }
      }
  }
}

// ---------------- final combine: out[t] = w0*y[a0] + w1*y[a1] ----------------
__global__ void combine_k(const float* __restrict__ ybuf, const int* __restrict__ aidx,
                          const float* __restrict__ tk_w, float* __restrict__ out) {
  const int i = blockIdx.x * 256 + threadIdx.x;   // N_TOK*512 threads, 4 cols each
  const int t = i >> 9, c = i & 511;
  const int a0 = aidx[t * 2], a1 = aidx[t * 2 + 1];
  const float w0 = tk_w[t * 2], w1 = tk_w[t * 2 + 1];
  const float4 v0 = ((const float4*)(ybuf + (size_t)a0 * DMODEL))[c];
  const float4 v1 = ((const float4*)(ybuf + (size_t)a1 * DMODEL))[c];
  float4 o;
  o.x = w0 * v0.x + w1 * v1.x;
  o.y = w0 * v0.y + w1 * v1.y;
  o.z = w0 * v0.z + w1 * v1.z;
  o.w = w0 * v0.w + w1 * v1.w;
  ((float4*)(out + (size_t)t * DMODEL))[c] = o;
}

extern "C" void kernel_launch(void* const* d_in, const int* in_sizes, int n_in,
                              void* d_out, int out_size, void* d_ws, size_t ws_size,
                              hipStream_t stream) {
  const float* x  = (const float*)d_in[0];
  const float* rw = (const float*)d_in[1];
  const float* gw = (const float*)d_in[2];
  const float* uw = (const float*)d_in[3];
  const float* dw = (const float*)d_in[4];
  float* out = (float*)d_out;

  char* ws = (char*)d_ws;
  size_t o = 0;
  auto alloc = [&](size_t bytes) {
    void* p = ws + o;
    o = (o + bytes + 255) & ~(size_t)255;
    return p;
  };

  const size_t guw_bytes  = (size_t)NEXP * NGU * DMODEL * 2;          // 201.3 MB
  const size_t ybuf_bytes = (size_t)(ATOT + 256) * DMODEL * 4;        // 270.5 MB
  bf16*  xb       = (bf16*)alloc((size_t)N_TOK * DMODEL * 2);         // 67 MB
  void*  uni      = alloc(ybuf_bytes > guw_bytes ? ybuf_bytes : guw_bytes);
  bf16*  guw      = (bf16*)uni;     // live: cvt..gemm1
  float* ybuf     = (float*)uni;    // live: gemm2..combine (gemm1 done with guw by then)
  bf16*  dwb      = (bf16*)alloc((size_t)NEXP * DMODEL * FFH * 2);    // 100.7 MB
  bf16*  hbuf     = (bf16*)alloc((size_t)(ATOT + 256) * FFH * 2);     // 202.9 MB
  int*   tok_list = (int*)alloc((ATOT + 256) * 4);
  float* w_list   = (float*)alloc((ATOT + 256) * 4);
  int*   tk_e     = (int*)alloc((size_t)N_TOK * 2 * 4);
  float* tk_w     = (float*)alloc((size_t)N_TOK * 2 * 4);
  int*   aidx     = (int*)alloc((size_t)N_TOK * 2 * 4);
  int*   cnt      = (int*)alloc(64);
  int*   offs     = (int*)alloc(64);
  int*   cnt2     = (int*)alloc(64);

  hipMemsetAsync(cnt, 0, 64, stream);
  hipMemsetAsync(cnt2, 0, 64, stream);

  // conversions
  {
    long n4 = (long)N_TOK * DMODEL / 4;
    cvt_f32_bf16<<<(unsigned)(n4 / 256), 256, 0, stream>>>(x, xb, n4);
  }
  cvt_guw<<<(unsigned)((long)NEXP * NGU * DMODEL / 8 / 256), 256, 0, stream>>>(gw, uw, guw);
  {
    long n4 = (long)NEXP * DMODEL * FFH / 4;
    cvt_f32_bf16<<<(unsigned)(n4 / 256), 256, 0, stream>>>(dw, dwb, n4);
  }

  // routing
  router_k<<<N_TOK / 4, 256, 0, stream>>>(x, rw, tk_e, tk_w, cnt);
  offs_k<<<1, 64, 0, stream>>>(cnt, offs);
  scatter_k<<<N_TOK / 256, 256, 0, stream>>>(tk_e, tk_w, offs, cnt2, tok_list, w_list, aidx);

  // expert GEMMs (m-grid covers worst case cn=16384 -> 64 tiles; empty blocks exit)
  gemm_moe<0><<<dim3(NGU / 256, 64, NEXP), 512, 0, stream>>>(
      xb, guw, hbuf, nullptr, tok_list, cnt, offs);
  gemm_moe<1><<<dim3(DMODEL / 256, 64, NEXP), 512, 0, stream>>>(
      hbuf, dwb, nullptr, ybuf, tok_list, cnt, offs);

  // combine (fully overwrites d_out every call)
  combine_k<<<N_TOK * 512 / 256, 256, 0, stream>>>(ybuf, aidx, tk_w, out);
}